// Round 2
// baseline (67966.113 us; speedup 1.0000x reference)
//
#include <hip/hip_runtime.h>

#define H    50
#define T    65536
#define NTHREADS 512

// ws layout (floats) — unchanged from previous (verified) version.
#define WC1_OFF 0        // 200*64
#define WC2_OFF 12800    // 200*128
#define BC1_OFF 38400    // 200
#define BC2_OFF 38600    // 200

// Prep: permute rows (orig r = gate*50+j  ->  new r' = j*4+gate) and pad cols.
// Wc1: 200 x 64  : cols 0..6 = W_ih1[:,0:7], col 7 = W_ih1[:,7] (err), 8..57 = W_hh1, 58..63 = 0
// Wc2: 200 x 128 : cols 0..49 = W_ih2, 50..99 = W_hh2, 100..127 = 0
__global__ void prep_kernel(const float* __restrict__ Wih1, const float* __restrict__ Whh1,
                            const float* __restrict__ bih1, const float* __restrict__ bhh1,
                            const float* __restrict__ Wih2, const float* __restrict__ Whh2,
                            const float* __restrict__ bih2, const float* __restrict__ bhh2,
                            float* __restrict__ ws) {
  int idx = blockIdx.x * blockDim.x + threadIdx.x;
  if (idx < 200 * 64) {
    int nr = idx >> 6, c = idx & 63;
    int j = nr >> 2, gate = nr & 3, r = gate * 50 + j;
    float v = 0.f;
    if (c < 8) v = Wih1[r * 8 + c];
    else if (c < 58) v = Whh1[r * 50 + (c - 8)];
    ws[WC1_OFF + idx] = v;
  }
  if (idx < 200 * 128) {
    int nr = idx >> 7, c = idx & 127;
    int j = nr >> 2, gate = nr & 3, r = gate * 50 + j;
    float v = 0.f;
    if (c < 50) v = Wih2[r * 50 + c];
    else if (c < 100) v = Whh2[r * 50 + (c - 50)];
    ws[WC2_OFF + idx] = v;
  }
  if (idx < 200) {
    int j = idx >> 2, gate = idx & 3, r = gate * 50 + j;
    ws[BC1_OFF + idx] = bih1[r] + bhh1[r];
    ws[BC2_OFF + idx] = bih2[r] + bhh2[r];
  }
}

__device__ __forceinline__ float sigm(float x) {
  return __builtin_amdgcn_rcpf(1.f + __expf(-x));
}
__device__ __forceinline__ float tanh_(float x) {
  return 1.f - 2.f * __builtin_amdgcn_rcpf(1.f + __expf(2.f * x));
}
// LDS-only barrier: no vmcnt drain, so global prefetch loads and y-stores
// pipeline across steps.
__device__ __forceinline__ void bar() {
  asm volatile("s_waitcnt lgkmcnt(0)\n\ts_barrier" ::: "memory");
}
// 0xB1 = quad_perm(1,0,3,2) = xor1 ; 0x4E = quad_perm(2,3,0,1) = xor2
// 0x141 = row_half_mirror (completes 8-lane reduce after xor1+xor2)
// 0x140 = row_mirror (completes 16-lane reduce)
template<int CTRL>
__device__ __forceinline__ float dpp_add(float x) {
  int y = __builtin_amdgcn_mov_dpp(__float_as_int(x), CTRL, 0xF, 0xF, true);
  return x + __int_as_float(y);
}
template<int CTRL>
__device__ __forceinline__ float dpp_mov(float x) {
  return __int_as_float(__builtin_amdgcn_mov_dpp(__float_as_int(x), CTRL, 0xF, 0xF, true));
}

// ============================================================================
// Same 2-phase schedule as round 0, but weights live in NAMED float4 registers
// (w0..w24) with zero local arrays and zero lambdas: round-0 rocprof showed
// VGPR_Count=84 with a 100-float per-lane array -> the array was in SCRATCH,
// re-read from L2 every timestep (~168 KB/step ~ 1300 cy/step). All phase code
// is macro-expanded straight-line so every access is compile-time-constant.
//
// Lane roles (512 threads):
//   tid 0..255   (waves 0-3): cell-2 row-per-lane (row=tid, rows>=200 dead),
//                             w0..w24 = Wc2 row (100 floats).
//   tid 256..511 (waves 4-7): cell-1 partial for t+1 (row=tid-256),
//                             w0..w15 = Wc1 row (64 floats), w16..w24 = 0.
//   tid 0..63    (wave 0)   : phase-2 worker (y, err, cell-1 gates, h1/c1).
//   tid 504..511 (wave 7)   : x prefetch, depth-2.
// ============================================================================

#define FQ(i) { float4 u4 = U4[i];                                   \
    a0 += w##i.x * u4.x; a1 += w##i.y * u4.y;                        \
    a2 += w##i.z * u4.z; a3 += w##i.w * u4.w; }

#define CELL2(par) {                                                 \
    const float4* U4 = (const float4*)CIN[par];                      \
    float a0 = 0.f, a1 = 0.f, a2 = 0.f, a3 = 0.f;                    \
    FQ(0) FQ(1) FQ(2) FQ(3) FQ(4) FQ(5) FQ(6) FQ(7) FQ(8) FQ(9)     \
    FQ(10) FQ(11) FQ(12) FQ(13) FQ(14) FQ(15) FQ(16) FQ(17) FQ(18)  \
    FQ(19) FQ(20) FQ(21) FQ(22) FQ(23) FQ(24)                        \
    float aa = ((a0 + a1) + (a2 + a3)) + b2h;                        \
    float act = aA + bA * __builtin_amdgcn_rcpf(1.f + __expf(sA * aa)); \
    float x1 = dpp_mov<0xB1>(act);                                   \
    float x2 = dpp_mov<0x4E>(act);                                   \
    float x3 = dpp_mov<0x4E>(x1);                                    \
    if ((tid & 3) == 0) {                                            \
      c2 = x1 * c2 + act * x2;                                       \
      float h2 = x3 * tanh_(c2);                                     \
      int u = tid >> 2;                                              \
      CIN[(par) ^ 1][50 + u] = h2;                                   \
      WY[u] = wo * h2;                                               \
    } }

#define HELPER(par) {                                                \
    const float4* U4 = (const float4*)AIN[(par) ^ 1];                \
    float a0 = 0.f, a1 = 0.f, a2 = 0.f, a3 = 0.f;                    \
    FQ(0) FQ(1) FQ(2) FQ(3) FQ(4) FQ(5) FQ(6) FQ(7) FQ(8) FQ(9)     \
    FQ(10) FQ(11) FQ(12) FQ(13) FQ(14) FQ(15)                        \
    PART[tid - 256] = ((a0 + a1) + (a2 + a3)) + b1h; }

#define PHASE2(t, par, doY) {                                        \
    if (tid < 64) {                                                  \
      float4 pq = *(const float4*)&PART[4 * tid];                    \
      if (doY) {                                                     \
        float v = WY[tid];                                           \
        float actd = ACT4[(t) & 3];                                  \
        v = dpp_add<0xB1>(v); v = dpp_add<0x4E>(v);                  \
        v = dpp_add<0x141>(v); v = dpp_add<0x140>(v);                \
        v = v + __int_as_float(__builtin_amdgcn_ds_swizzle(__float_as_int(v), 0x401F)); \
        float vlo = __int_as_float(__builtin_amdgcn_readlane(__float_as_int(v), 0));  \
        float vhi = __int_as_float(__builtin_amdgcn_readlane(__float_as_int(v), 32)); \
        float y = vlo + vhi + bo;                                    \
        if (tid == 0) out[t] = y;                                    \
        err = 0.9f * err + 0.1f * (actd - y);                        \
      }                                                              \
      float gi = sigm (pq.x + werr0 * err);                          \
      float gf = sigm (pq.y + werr1 * err);                          \
      float gg = tanh_(pq.z + werr2 * err);                          \
      float go = sigm (pq.w + werr3 * err);                          \
      c1 = gf * c1 + gi * gg;                                        \
      float h1 = go * tanh_(c1);                                     \
      if (tid < 50) {                                                \
        CIN[(par) ^ 1][tid] = h1;                                    \
        AIN[par][8 + tid]   = h1;                                    \
      }                                                              \
    } else if (tid >= 504) {                                         \
      int c = tid - 504;                                             \
      if (c < 7) AIN[par][c] = xr; else ACT4[((t) + 2) & 3] = xr;    \
      int nt = ((t) + 3 < T) ? (t) + 3 : T - 1;                      \
      xr = xseq[nt * 8 + c];                                         \
    } }

__launch_bounds__(NTHREADS, 2)   // 2 waves/EU -> 256-VGPR budget (need ~150)
__global__ void lstm_kernel(const float* __restrict__ xseq,
                            const float* __restrict__ ws,
                            const float* __restrict__ Wout,
                            const float* __restrict__ bout,
                            float* __restrict__ out) {
  // Dense layouts; broadcast reads -> no bank conflicts (R1 counter: ~0).
  // Pads must stay exactly 0 forever.
  __shared__ __align__(16) float AIN[2][64];    // [x(7) | 0@7 | h1(50) | 0(6)]
  __shared__ __align__(16) float CIN[2][128];   // [h1(50) | h2(50) | pad]
  __shared__ __align__(16) float PART[256];     // cell-1 partial gates (rows)
  __shared__ __align__(16) float WY[64];        // wo[u]*h2[u], 50..63 = 0
  __shared__ float ACT4[4];                     // act_dist ring, depth 4

  const int tid = threadIdx.x;
  const float* Wc1 = ws + WC1_OFF;
  const float* Wc2 = ws + WC2_OFF;
  const float* bc1 = ws + BC1_OFF;
  const float* bc2 = ws + BC2_OFF;

  for (int i = tid; i < 2 * 64;  i += NTHREADS) ((float*)AIN)[i] = 0.f;
  for (int i = tid; i < 2 * 128; i += NTHREADS) ((float*)CIN)[i] = 0.f;
  for (int i = tid; i < 256;     i += NTHREADS) PART[i] = 0.f;
  if (tid < 64) WY[tid] = 0.f;
  if (tid < 4)  ACT4[tid] = 0.f;

  // Named weight registers (overlaid): cell-2 lanes use w0..w24,
  // helper lanes use w0..w15 (rest zero). No arrays -> no scratch.
  float4 w0, w1, w2, w3, w4, w5, w6, w7, w8, w9, w10, w11, w12,
         w13, w14, w15, w16, w17, w18, w19, w20, w21, w22, w23, w24;
  float c1 = 0.f, c2 = 0.f, err = 0.f, xr = 0.f;
  float b2h = 0.f, b1h = 0.f, wo = 0.f, bo = 0.f;
  float werr0 = 0.f, werr1 = 0.f, werr2 = 0.f, werr3 = 0.f;
  // unified activation: act = aA + bA * rcp(1 + exp(sA*x))
  // gate (tid&3)==2 (g): tanh -> sA=2,aA=1,bA=-2 ; else sigmoid -> sA=-1,aA=0,bA=1
  float sA = -1.f, aA = 0.f, bA = 1.f;

  const float4 z4 = make_float4(0.f, 0.f, 0.f, 0.f);
  w16 = z4; w17 = z4; w18 = z4; w19 = z4; w20 = z4;
  w21 = z4; w22 = z4; w23 = z4; w24 = z4;

  if (tid < 256) {                       // cell-2 lanes, row = tid
    const int row = tid;
    if ((tid & 3) == 2) { sA = 2.f; aA = 1.f; bA = -2.f; }
    if (row < 200) {
      const float4* s2 = (const float4*)&Wc2[row * 128];
      w0  = s2[0];  w1  = s2[1];  w2  = s2[2];  w3  = s2[3];  w4  = s2[4];
      w5  = s2[5];  w6  = s2[6];  w7  = s2[7];  w8  = s2[8];  w9  = s2[9];
      w10 = s2[10]; w11 = s2[11]; w12 = s2[12]; w13 = s2[13]; w14 = s2[14];
      w15 = s2[15]; w16 = s2[16]; w17 = s2[17]; w18 = s2[18]; w19 = s2[19];
      w20 = s2[20]; w21 = s2[21]; w22 = s2[22]; w23 = s2[23]; w24 = s2[24];
      b2h = bc2[row];
    } else {                             // dead pad rows -> exact zeros
      w0 = z4; w1 = z4; w2 = z4; w3 = z4; w4 = z4; w5 = z4; w6 = z4;
      w7 = z4; w8 = z4; w9 = z4; w10 = z4; w11 = z4; w12 = z4; w13 = z4;
      w14 = z4; w15 = z4;
    }
    if ((tid & 3) == 0) {
      int u = tid >> 2;
      wo = (u < 50) ? Wout[u] : 0.f;
    }
    if (tid < 64) {                      // wave 0: phase-2 worker extras
      bo = bout[0];
      if (tid < 50) {
        werr0 = Wc1[(4 * tid + 0) * 64 + 7];
        werr1 = Wc1[(4 * tid + 1) * 64 + 7];
        werr2 = Wc1[(4 * tid + 2) * 64 + 7];
        werr3 = Wc1[(4 * tid + 3) * 64 + 7];
      }
    }
  } else {                               // helper lanes, row = tid-256
    const int row = tid - 256;
    if (row < 200) {
      const float4* s1 = (const float4*)&Wc1[row * 64];
      w0  = s1[0];  w1  = s1[1];  w2  = s1[2];  w3  = s1[3];
      w4  = s1[4];  w5  = s1[5];  w6  = s1[6];  w7  = s1[7];
      w8  = s1[8];  w9  = s1[9];  w10 = s1[10]; w11 = s1[11];
      w12 = s1[12]; w13 = s1[13]; w14 = s1[14]; w15 = s1[15];
      b1h = bc1[row];
    } else {
      w0 = z4; w1 = z4; w2 = z4; w3 = z4; w4 = z4; w5 = z4; w6 = z4;
      w7 = z4; w8 = z4; w9 = z4; w10 = z4; w11 = z4; w12 = z4; w13 = z4;
      w14 = z4; w15 = z4;
    }
  }
  __syncthreads();
  // preload x(0) AFTER zeroing (avoid zero-vs-preload race), stage x(1) in xr
  if (tid >= 504) {
    int c = tid - 504;
    float v0 = xseq[c];
    if (c < 7) AIN[0][c] = v0; else ACT4[0] = v0;
    xr = xseq[8 + c];
  }
  __syncthreads();

  // ---- prologue: pseudo-iteration t = -1 (par = 1), no y/err yet ----
  if (tid >= 256) HELPER(1)              // PART(0) from AIN[0] = [x(0); h1=0]
  bar();
  PHASE2(-1, 1, false)                   // h1(0)->CIN[0],AIN[1]; x(1)->AIN[1]
  bar();

  #pragma unroll 1
  for (int t = 0; t < T; t += 2) {
    if (tid < 256) CELL2(0) else HELPER(0)
    bar();
    PHASE2(t, 0, true)
    bar();
    if (tid < 256) CELL2(1) else HELPER(1)
    bar();
    PHASE2(t + 1, 1, true)
    bar();
  }
}

extern "C" void kernel_launch(void* const* d_in, const int* in_sizes, int n_in,
                              void* d_out, int out_size, void* d_ws, size_t ws_size,
                              hipStream_t stream) {
  const float* xseq = (const float*)d_in[0];
  const float* Wih1 = (const float*)d_in[1];
  const float* Whh1 = (const float*)d_in[2];
  const float* bih1 = (const float*)d_in[3];
  const float* bhh1 = (const float*)d_in[4];
  const float* Wih2 = (const float*)d_in[5];
  const float* Whh2 = (const float*)d_in[6];
  const float* bih2 = (const float*)d_in[7];
  const float* bhh2 = (const float*)d_in[8];
  const float* Wout = (const float*)d_in[9];
  const float* bout = (const float*)d_in[10];
  float* ws = (float*)d_ws;

  prep_kernel<<<100, 256, 0, stream>>>(Wih1, Whh1, bih1, bhh1,
                                       Wih2, Whh2, bih2, bhh2, ws);
  lstm_kernel<<<1, NTHREADS, 0, stream>>>(xseq, ws, Wout, bout, (float*)d_out);
}

// Round 4
// 61059.119 us; speedup vs baseline: 1.1131x; 1.1131x over previous
//
#include <hip/hip_runtime.h>

#define H    50
#define T    65536
#define NTHREADS 512

// ws layout (floats) — unchanged from previous (verified) version.
#define WC1_OFF 0        // 200*64
#define WC2_OFF 12800    // 200*128
#define BC1_OFF 38400    // 200
#define BC2_OFF 38600    // 200

// Prep: permute rows (orig r = gate*50+j  ->  new r' = j*4+gate) and pad cols.
// Wc1: 200 x 64  : cols 0..6 = W_ih1[:,0:7], col 7 = W_ih1[:,7] (err), 8..57 = W_hh1, 58..63 = 0
// Wc2: 200 x 128 : cols 0..49 = W_ih2, 50..99 = W_hh2, 100..127 = 0
__global__ void prep_kernel(const float* __restrict__ Wih1, const float* __restrict__ Whh1,
                            const float* __restrict__ bih1, const float* __restrict__ bhh1,
                            const float* __restrict__ Wih2, const float* __restrict__ Whh2,
                            const float* __restrict__ bih2, const float* __restrict__ bhh2,
                            float* __restrict__ ws) {
  int idx = blockIdx.x * blockDim.x + threadIdx.x;
  if (idx < 200 * 64) {
    int nr = idx >> 6, c = idx & 63;
    int j = nr >> 2, gate = nr & 3, r = gate * 50 + j;
    float v = 0.f;
    if (c < 8) v = Wih1[r * 8 + c];
    else if (c < 58) v = Whh1[r * 50 + (c - 8)];
    ws[WC1_OFF + idx] = v;
  }
  if (idx < 200 * 128) {
    int nr = idx >> 7, c = idx & 127;
    int j = nr >> 2, gate = nr & 3, r = gate * 50 + j;
    float v = 0.f;
    if (c < 50) v = Wih2[r * 50 + c];
    else if (c < 100) v = Whh2[r * 50 + (c - 50)];
    ws[WC2_OFF + idx] = v;
  }
  if (idx < 200) {
    int j = idx >> 2, gate = idx & 3, r = gate * 50 + j;
    ws[BC1_OFF + idx] = bih1[r] + bhh1[r];
    ws[BC2_OFF + idx] = bih2[r] + bhh2[r];
  }
}

__device__ __forceinline__ float sigm(float x) {
  return __builtin_amdgcn_rcpf(1.f + __expf(-x));
}
__device__ __forceinline__ float tanh_(float x) {
  return 1.f - 2.f * __builtin_amdgcn_rcpf(1.f + __expf(2.f * x));
}
// LDS-only barrier: no vmcnt drain, so global prefetch loads and y-stores
// pipeline across steps.
__device__ __forceinline__ void bar() {
  asm volatile("s_waitcnt lgkmcnt(0)\n\ts_barrier" ::: "memory");
}
// 0xB1 = quad_perm(1,0,3,2) = xor1 ; 0x4E = quad_perm(2,3,0,1) = xor2
// 0x141 = row_half_mirror (completes 8-lane reduce after xor1+xor2)
// 0x140 = row_mirror (completes 16-lane reduce)
template<int CTRL>
__device__ __forceinline__ float dpp_add(float x) {
  int y = __builtin_amdgcn_mov_dpp(__float_as_int(x), CTRL, 0xF, 0xF, true);
  return x + __int_as_float(y);
}
template<int CTRL>
__device__ __forceinline__ float dpp_mov(float x) {
  return __int_as_float(__builtin_amdgcn_mov_dpp(__float_as_int(x), CTRL, 0xF, 0xF, true));
}

// ============================================================================
// Identical to round 2 EXCEPT: amdgpu_waves_per_eu(2,2).
// (Round 3 was this exact kernel but the container failed before running it —
// resubmitting unchanged so the attribution stays clean.)
//
// R1/R2 rocprof: VGPR_Count=84 in BOTH structurally different kernels.
// 512 VGPRs/SIMD / 84 = 6 waves/EU -> the register allocator is targeting
// occupancy 6 (launch_bounds' 2nd arg only sets the MINIMUM waves/EU, i.e. a
// VGPR<=256 guarantee; the heuristic may still aim higher). At 84 VGPRs the
// ~100 weight floats/lane spill to AGPRs: no memory traffic (FETCH tiny, bank
// conflicts 0 — matches counters) but one v_accvgpr_read VALU op per weight
// per step: VALUBusy 0.14%*256 ~ 36% of the CU ~ 900 issue-cy/step vs ~300
// algorithmic — the 3x inflation IS the spill cost, and explains why two
// different schedules land at the same ~2500 cy/step.
// amdgpu_waves_per_eu(2,2) caps the occupancy TARGET at 2 (one 8-wave block =
// exactly 2 waves/EU; grid=1 so higher occupancy was worthless), freeing the
// allocator to keep all weights in arch VGPRs.
//
// Lane roles (512 threads):
//   tid 0..255   (waves 0-3): cell-2 row-per-lane (row=tid, rows>=200 dead),
//                             w0..w24 = Wc2 row (100 floats).
//   tid 256..511 (waves 4-7): cell-1 partial for t+1 (row=tid-256),
//                             w0..w15 = Wc1 row (64 floats), w16..w24 = 0.
//   tid 0..63    (wave 0)   : phase-2 worker (y, err, cell-1 gates, h1/c1).
//   tid 504..511 (wave 7)   : x prefetch, depth-2.
// ============================================================================

#define FQ(i) { float4 u4 = U4[i];                                   \
    a0 += w##i.x * u4.x; a1 += w##i.y * u4.y;                        \
    a2 += w##i.z * u4.z; a3 += w##i.w * u4.w; }

#define CELL2(par) {                                                 \
    const float4* U4 = (const float4*)CIN[par];                      \
    float a0 = 0.f, a1 = 0.f, a2 = 0.f, a3 = 0.f;                    \
    FQ(0) FQ(1) FQ(2) FQ(3) FQ(4) FQ(5) FQ(6) FQ(7) FQ(8) FQ(9)     \
    FQ(10) FQ(11) FQ(12) FQ(13) FQ(14) FQ(15) FQ(16) FQ(17) FQ(18)  \
    FQ(19) FQ(20) FQ(21) FQ(22) FQ(23) FQ(24)                        \
    float aa = ((a0 + a1) + (a2 + a3)) + b2h;                        \
    float act = aA + bA * __builtin_amdgcn_rcpf(1.f + __expf(sA * aa)); \
    float x1 = dpp_mov<0xB1>(act);                                   \
    float x2 = dpp_mov<0x4E>(act);                                   \
    float x3 = dpp_mov<0x4E>(x1);                                    \
    if ((tid & 3) == 0) {                                            \
      c2 = x1 * c2 + act * x2;                                       \
      float h2 = x3 * tanh_(c2);                                     \
      int u = tid >> 2;                                              \
      CIN[(par) ^ 1][50 + u] = h2;                                   \
      WY[u] = wo * h2;                                               \
    } }

#define HELPER(par) {                                                \
    const float4* U4 = (const float4*)AIN[(par) ^ 1];                \
    float a0 = 0.f, a1 = 0.f, a2 = 0.f, a3 = 0.f;                    \
    FQ(0) FQ(1) FQ(2) FQ(3) FQ(4) FQ(5) FQ(6) FQ(7) FQ(8) FQ(9)     \
    FQ(10) FQ(11) FQ(12) FQ(13) FQ(14) FQ(15)                        \
    PART[tid - 256] = ((a0 + a1) + (a2 + a3)) + b1h; }

#define PHASE2(t, par, doY) {                                        \
    if (tid < 64) {                                                  \
      float4 pq = *(const float4*)&PART[4 * tid];                    \
      if (doY) {                                                     \
        float v = WY[tid];                                           \
        float actd = ACT4[(t) & 3];                                  \
        v = dpp_add<0xB1>(v); v = dpp_add<0x4E>(v);                  \
        v = dpp_add<0x141>(v); v = dpp_add<0x140>(v);                \
        v = v + __int_as_float(__builtin_amdgcn_ds_swizzle(__float_as_int(v), 0x401F)); \
        float vlo = __int_as_float(__builtin_amdgcn_readlane(__float_as_int(v), 0));  \
        float vhi = __int_as_float(__builtin_amdgcn_readlane(__float_as_int(v), 32)); \
        float y = vlo + vhi + bo;                                    \
        if (tid == 0) out[t] = y;                                    \
        err = 0.9f * err + 0.1f * (actd - y);                        \
      }                                                              \
      float gi = sigm (pq.x + werr0 * err);                          \
      float gf = sigm (pq.y + werr1 * err);                          \
      float gg = tanh_(pq.z + werr2 * err);                          \
      float go = sigm (pq.w + werr3 * err);                          \
      c1 = gf * c1 + gi * gg;                                        \
      float h1 = go * tanh_(c1);                                     \
      if (tid < 50) {                                                \
        CIN[(par) ^ 1][tid] = h1;                                    \
        AIN[par][8 + tid]   = h1;                                    \
      }                                                              \
    } else if (tid >= 504) {                                         \
      int c = tid - 504;                                             \
      if (c < 7) AIN[par][c] = xr; else ACT4[((t) + 2) & 3] = xr;    \
      int nt = ((t) + 3 < T) ? (t) + 3 : T - 1;                      \
      xr = xseq[nt * 8 + c];                                         \
    } }

__launch_bounds__(NTHREADS)
__attribute__((amdgpu_waves_per_eu(2, 2)))   // cap occupancy TARGET -> 256-VGPR budget actually used
__global__ void lstm_kernel(const float* __restrict__ xseq,
                            const float* __restrict__ ws,
                            const float* __restrict__ Wout,
                            const float* __restrict__ bout,
                            float* __restrict__ out) {
  // Dense layouts; broadcast reads -> no bank conflicts (R1 counter: ~0).
  // Pads must stay exactly 0 forever.
  __shared__ __align__(16) float AIN[2][64];    // [x(7) | 0@7 | h1(50) | 0(6)]
  __shared__ __align__(16) float CIN[2][128];   // [h1(50) | h2(50) | pad]
  __shared__ __align__(16) float PART[256];     // cell-1 partial gates (rows)
  __shared__ __align__(16) float WY[64];        // wo[u]*h2[u], 50..63 = 0
  __shared__ float ACT4[4];                     // act_dist ring, depth 4

  const int tid = threadIdx.x;
  const float* Wc1 = ws + WC1_OFF;
  const float* Wc2 = ws + WC2_OFF;
  const float* bc1 = ws + BC1_OFF;
  const float* bc2 = ws + BC2_OFF;

  for (int i = tid; i < 2 * 64;  i += NTHREADS) ((float*)AIN)[i] = 0.f;
  for (int i = tid; i < 2 * 128; i += NTHREADS) ((float*)CIN)[i] = 0.f;
  for (int i = tid; i < 256;     i += NTHREADS) PART[i] = 0.f;
  if (tid < 64) WY[tid] = 0.f;
  if (tid < 4)  ACT4[tid] = 0.f;

  // Named weight registers (overlaid): cell-2 lanes use w0..w24,
  // helper lanes use w0..w15 (rest zero). No arrays -> no scratch.
  float4 w0, w1, w2, w3, w4, w5, w6, w7, w8, w9, w10, w11, w12,
         w13, w14, w15, w16, w17, w18, w19, w20, w21, w22, w23, w24;
  float c1 = 0.f, c2 = 0.f, err = 0.f, xr = 0.f;
  float b2h = 0.f, b1h = 0.f, wo = 0.f, bo = 0.f;
  float werr0 = 0.f, werr1 = 0.f, werr2 = 0.f, werr3 = 0.f;
  // unified activation: act = aA + bA * rcp(1 + exp(sA*x))
  // gate (tid&3)==2 (g): tanh -> sA=2,aA=1,bA=-2 ; else sigmoid -> sA=-1,aA=0,bA=1
  float sA = -1.f, aA = 0.f, bA = 1.f;

  const float4 z4 = make_float4(0.f, 0.f, 0.f, 0.f);
  w16 = z4; w17 = z4; w18 = z4; w19 = z4; w20 = z4;
  w21 = z4; w22 = z4; w23 = z4; w24 = z4;

  if (tid < 256) {                       // cell-2 lanes, row = tid
    const int row = tid;
    if ((tid & 3) == 2) { sA = 2.f; aA = 1.f; bA = -2.f; }
    if (row < 200) {
      const float4* s2 = (const float4*)&Wc2[row * 128];
      w0  = s2[0];  w1  = s2[1];  w2  = s2[2];  w3  = s2[3];  w4  = s2[4];
      w5  = s2[5];  w6  = s2[6];  w7  = s2[7];  w8  = s2[8];  w9  = s2[9];
      w10 = s2[10]; w11 = s2[11]; w12 = s2[12]; w13 = s2[13]; w14 = s2[14];
      w15 = s2[15]; w16 = s2[16]; w17 = s2[17]; w18 = s2[18]; w19 = s2[19];
      w20 = s2[20]; w21 = s2[21]; w22 = s2[22]; w23 = s2[23]; w24 = s2[24];
      b2h = bc2[row];
    } else {                             // dead pad rows -> exact zeros
      w0 = z4; w1 = z4; w2 = z4; w3 = z4; w4 = z4; w5 = z4; w6 = z4;
      w7 = z4; w8 = z4; w9 = z4; w10 = z4; w11 = z4; w12 = z4; w13 = z4;
      w14 = z4; w15 = z4;
    }
    if ((tid & 3) == 0) {
      int u = tid >> 2;
      wo = (u < 50) ? Wout[u] : 0.f;
    }
    if (tid < 64) {                      // wave 0: phase-2 worker extras
      bo = bout[0];
      if (tid < 50) {
        werr0 = Wc1[(4 * tid + 0) * 64 + 7];
        werr1 = Wc1[(4 * tid + 1) * 64 + 7];
        werr2 = Wc1[(4 * tid + 2) * 64 + 7];
        werr3 = Wc1[(4 * tid + 3) * 64 + 7];
      }
    }
  } else {                               // helper lanes, row = tid-256
    const int row = tid - 256;
    if (row < 200) {
      const float4* s1 = (const float4*)&Wc1[row * 64];
      w0  = s1[0];  w1  = s1[1];  w2  = s1[2];  w3  = s1[3];
      w4  = s1[4];  w5  = s1[5];  w6  = s1[6];  w7  = s1[7];
      w8  = s1[8];  w9  = s1[9];  w10 = s1[10]; w11 = s1[11];
      w12 = s1[12]; w13 = s1[13]; w14 = s1[14]; w15 = s1[15];
      b1h = bc1[row];
    } else {
      w0 = z4; w1 = z4; w2 = z4; w3 = z4; w4 = z4; w5 = z4; w6 = z4;
      w7 = z4; w8 = z4; w9 = z4; w10 = z4; w11 = z4; w12 = z4; w13 = z4;
      w14 = z4; w15 = z4;
    }
  }
  __syncthreads();
  // preload x(0) AFTER zeroing (avoid zero-vs-preload race), stage x(1) in xr
  if (tid >= 504) {
    int c = tid - 504;
    float v0 = xseq[c];
    if (c < 7) AIN[0][c] = v0; else ACT4[0] = v0;
    xr = xseq[8 + c];
  }
  __syncthreads();

  // ---- prologue: pseudo-iteration t = -1 (par = 1), no y/err yet ----
  if (tid >= 256) HELPER(1)              // PART(0) from AIN[0] = [x(0); h1=0]
  bar();
  PHASE2(-1, 1, false)                   // h1(0)->CIN[0],AIN[1]; x(1)->AIN[1]
  bar();

  #pragma unroll 1
  for (int t = 0; t < T; t += 2) {
    if (tid < 256) CELL2(0) else HELPER(0)
    bar();
    PHASE2(t, 0, true)
    bar();
    if (tid < 256) CELL2(1) else HELPER(1)
    bar();
    PHASE2(t + 1, 1, true)
    bar();
  }
}

extern "C" void kernel_launch(void* const* d_in, const int* in_sizes, int n_in,
                              void* d_out, int out_size, void* d_ws, size_t ws_size,
                              hipStream_t stream) {
  const float* xseq = (const float*)d_in[0];
  const float* Wih1 = (const float*)d_in[1];
  const float* Whh1 = (const float*)d_in[2];
  const float* bih1 = (const float*)d_in[3];
  const float* bhh1 = (const float*)d_in[4];
  const float* Wih2 = (const float*)d_in[5];
  const float* Whh2 = (const float*)d_in[6];
  const float* bih2 = (const float*)d_in[7];
  const float* bhh2 = (const float*)d_in[8];
  const float* Wout = (const float*)d_in[9];
  const float* bout = (const float*)d_in[10];
  float* ws = (float*)d_ws;

  prep_kernel<<<100, 256, 0, stream>>>(Wih1, Whh1, bih1, bhh1,
                                       Wih2, Whh2, bih2, bhh2, ws);
  lstm_kernel<<<1, NTHREADS, 0, stream>>>(xseq, ws, Wout, bout, (float*)d_out);
}